// Round 11
// baseline (170.030 us; speedup 1.0000x reference)
//
#include <hip/hip_runtime.h>

// Depthwise 21x21 Gaussian blur, reflect pad 10, 16x3x512x512 fp32.
// Separable: phi[j] = W[ch][10][j] / sqrt(W[ch][10][10]).
// R6 vs R4 (R5's b128-LDS experiment regressed: quad-mod-8 bank groups ->
// 8-way conflicts, 9.6M cyc; reverted to R4's proven scalar-b32 stride-53
// patterns): h-pass now reads its window DIRECTLY from global (reg-staged
// float4, halo re-reads are L1/L2 hits - FETCH has been flat 46MB all rounds),
// deleting sA staging (-45 LDS ops/thread), one barrier, and 17.7KB of LDS.
// sB-only LDS = 13.8KB -> 8 blocks/CU = 32 waves (max). Streaming accumulate
// keeps live VGPR ~45 under the (256,8) 64-reg cap.

constexpr int IMG = 512;
constexpr int KS  = 21;
constexpr int RAD = 10;
constexpr int TX  = 64;
constexpr int TY  = 32;
constexpr int HY  = TY + 2 * RAD;     // 52 h-filtered rows
constexpr int SB_STRIDE = 53;         // 53%32=21, coprime -> uniform 2-way (proven R4)

__device__ __forceinline__ int reflect512(int i) {
    i = (i < 0) ? -i : i;
    return (i >= IMG) ? 2 * IMG - 2 - i : i;
}

__global__ __launch_bounds__(256, 8) void gauss2d_sep(const float* __restrict__ x,
                                                      const float* __restrict__ W,
                                                      float* __restrict__ out)
{
    __shared__ float sB[TX * SB_STRIDE];   // [col][row] transposed, 13568 B

    const int tid = threadIdx.x;
    const int bx = blockIdx.x, by = blockIdx.y, bc = blockIdx.z;
    const int tx = bx * TX, ty = by * TY;
    const int ch = bc % 3;

    // Separable taps from the 2D weight; wave-uniform -> SGPRs.
    const float* wr = W + ch * (KS * KS) + RAD * KS;
    const float inv = 1.0f / sqrtf(wr[RAD]);
    float ph[KS];
    #pragma unroll
    for (int j = 0; j < KS; ++j)
        ph[j] = __int_as_float(__builtin_amdgcn_readfirstlane(__float_as_int(wr[j] * inv)));

    const float* __restrict__ xin = x + (size_t)bc * (IMG * IMG);

    // ---- Horizontal pass straight from global: 52 rows x 4 chunks of 16. ----
    // Window = 40 floats (cols tx+c0-12 .. tx+c0+27), taps hit w = i+2+j.
    if (tid < HY * 4) {
        const int r  = tid >> 2;
        const int c0 = (tid & 3) << 4;
        const int gr = reflect512(ty + r - RAD);
        const float* __restrict__ row = xin + (size_t)gr * IMG;

        float acc[16];
        #pragma unroll
        for (int i = 0; i < 16; ++i) acc[i] = 0.f;

        if (bx >= 1 && bx <= 6) {                      // no col reflect possible
            const float4* __restrict__ row4 =
                (const float4*)(row + (tx + c0 - 12)); // 16B-aligned
            #pragma unroll
            for (int k = 0; k < 10; ++k) {             // streaming: low live set
                const float4 v = row4[k];
                const float el[4] = {v.x, v.y, v.z, v.w};
                #pragma unroll
                for (int m = 0; m < 4; ++m) {
                    const int w = 4 * k + m;
                    #pragma unroll
                    for (int i = 0; i < 16; ++i) {
                        const int j = w - 2 - i;       // static -> guard folds
                        if (j >= 0 && j < KS) acc[i] += ph[j] * el[m];
                    }
                }
            }
        } else {                                        // bx 0 or 7: col reflect
            #pragma unroll
            for (int w = 0; w < 40; ++w) {
                const int gc = reflect512(tx + c0 - 12 + w);
                const float v = row[gc];
                #pragma unroll
                for (int i = 0; i < 16; ++i) {
                    const int j = w - 2 - i;
                    if (j >= 0 && j < KS) acc[i] += ph[j] * v;
                }
            }
        }
        #pragma unroll
        for (int i = 0; i < 16; ++i)
            sB[(c0 + i) * SB_STRIDE + r] = acc[i];     // 2-way max (proven)
    }
    __syncthreads();

    // ---- Vertical pass: col = tid&63, rows [(tid>>6)*8, +8). 256 tasks. ----
    {
        const int c  = tid & 63;
        const int r0 = (tid >> 6) << 3;
        const float* bcol = &sB[c * SB_STRIDE + r0];
        float win[28];
        #pragma unroll
        for (int k = 0; k < 28; ++k) win[k] = bcol[k]; // 2-way max (proven)
        float acc[8];
        #pragma unroll
        for (int i = 0; i < 8; ++i) {
            float a = ph[0] * win[i];
            #pragma unroll
            for (int j = 1; j < KS; ++j) a += ph[j] * win[i + j];
            acc[i] = a;
        }
        float* __restrict__ oimg = out + (size_t)bc * (IMG * IMG)
                                 + (size_t)(ty + r0) * IMG + (tx + c);
        #pragma unroll
        for (int i = 0; i < 8; ++i)
            oimg[i * IMG] = acc[i];                    // coalesced
    }
}

extern "C" void kernel_launch(void* const* d_in, const int* in_sizes, int n_in,
                              void* d_out, int out_size, void* d_ws, size_t ws_size,
                              hipStream_t stream) {
    const float* x = (const float*)d_in[0];
    const float* W = (const float*)d_in[1];
    float* out     = (float*)d_out;
    dim3 grid(IMG / TX, IMG / TY, 16 * 3);
    gauss2d_sep<<<grid, 256, 0, stream>>>(x, W, out);
}

// Round 13
// 167.314 us; speedup vs baseline: 1.0162x; 1.0162x over previous
//
#include <hip/hip_runtime.h>

// Depthwise 21x21 Gaussian blur, reflect pad 10, 16x3x512x512 fp32.
// Separable: phi[j] = W[ch][10][j] / sqrt(W[ch][10][10]).
// R7 vs R6 (R6 regressed 98us: launch_bounds(256,8) -> VGPR squeezed to 32
// (acc[16] spilled) + streaming load->fma chaining serialized the 10 global
// loads; VALUBusy 62->22%): (1) bounds (256,4) = 128-VGPR cap, ~70 live;
// (2) h-pass = load win[40] via 10 INDEPENDENT dwordx4, one vmcnt drain,
// then 336 guard-free FMAs (ILP restored). Structure otherwise = R6:
// no sA staging (halo re-reads are L1/L2 hits, FETCH flat 46MB all rounds),
// sB-only LDS 13.6KB, single barrier, stride-53 2-way patterns (proven R4).

constexpr int IMG = 512;
constexpr int KS  = 21;
constexpr int RAD = 10;
constexpr int TX  = 64;
constexpr int TY  = 32;
constexpr int HY  = TY + 2 * RAD;     // 52 h-filtered rows
constexpr int SB_STRIDE = 53;         // 53%32=21, coprime -> uniform 2-way (proven R4)

__device__ __forceinline__ int reflect512(int i) {
    i = (i < 0) ? -i : i;
    return (i >= IMG) ? 2 * IMG - 2 - i : i;
}

__global__ __launch_bounds__(256, 4) void gauss2d_sep(const float* __restrict__ x,
                                                      const float* __restrict__ W,
                                                      float* __restrict__ out)
{
    __shared__ float sB[TX * SB_STRIDE];   // [col][row] transposed, 13568 B

    const int tid = threadIdx.x;
    const int bx = blockIdx.x, by = blockIdx.y, bc = blockIdx.z;
    const int tx = bx * TX, ty = by * TY;
    const int ch = bc % 3;

    // Separable taps from the 2D weight; wave-uniform -> SGPRs.
    const float* wr = W + ch * (KS * KS) + RAD * KS;
    const float inv = 1.0f / sqrtf(wr[RAD]);
    float ph[KS];
    #pragma unroll
    for (int j = 0; j < KS; ++j)
        ph[j] = __int_as_float(__builtin_amdgcn_readfirstlane(__float_as_int(wr[j] * inv)));

    const float* __restrict__ xin = x + (size_t)bc * (IMG * IMG);

    // ---- Horizontal pass straight from global: 52 rows x 4 chunks of 16. ----
    // Window = 40 floats (cols tx+c0-12 .. tx+c0+27), taps hit w = i+2+j.
    if (tid < HY * 4) {
        const int r  = tid >> 2;
        const int c0 = (tid & 3) << 4;
        const int gr = reflect512(ty + r - RAD);
        const float* __restrict__ row = xin + (size_t)gr * IMG;

        float win[40];                                 // load-then-compute: all
        if (bx >= 1 && bx <= 6) {                      // loads independent (ILP)
            const float4* __restrict__ row4 =
                (const float4*)(row + (tx + c0 - 12)); // 16B-aligned
            #pragma unroll
            for (int k = 0; k < 10; ++k) {
                const float4 v = row4[k];
                win[4 * k]     = v.x;  win[4 * k + 1] = v.y;
                win[4 * k + 2] = v.z;  win[4 * k + 3] = v.w;
            }
        } else {                                        // bx 0 or 7: col reflect
            #pragma unroll
            for (int w = 0; w < 40; ++w)
                win[w] = row[reflect512(tx + c0 - 12 + w)];
        }

        float acc[16];
        #pragma unroll
        for (int i = 0; i < 16; ++i) {
            float a = ph[0] * win[i + 2];
            #pragma unroll
            for (int j = 1; j < KS; ++j) a += ph[j] * win[i + 2 + j];
            acc[i] = a;
        }
        #pragma unroll
        for (int i = 0; i < 16; ++i)
            sB[(c0 + i) * SB_STRIDE + r] = acc[i];     // 2-way max (proven)
    }
    __syncthreads();

    // ---- Vertical pass: col = tid&63, rows [(tid>>6)*8, +8). 256 tasks. ----
    {
        const int c  = tid & 63;
        const int r0 = (tid >> 6) << 3;
        const float* bcol = &sB[c * SB_STRIDE + r0];
        float win[28];
        #pragma unroll
        for (int k = 0; k < 28; ++k) win[k] = bcol[k]; // 2-way max (proven)
        float acc[8];
        #pragma unroll
        for (int i = 0; i < 8; ++i) {
            float a = ph[0] * win[i];
            #pragma unroll
            for (int j = 1; j < KS; ++j) a += ph[j] * win[i + j];
            acc[i] = a;
        }
        float* __restrict__ oimg = out + (size_t)bc * (IMG * IMG)
                                 + (size_t)(ty + r0) * IMG + (tx + c);
        #pragma unroll
        for (int i = 0; i < 8; ++i)
            oimg[i * IMG] = acc[i];                    // coalesced
    }
}

extern "C" void kernel_launch(void* const* d_in, const int* in_sizes, int n_in,
                              void* d_out, int out_size, void* d_ws, size_t ws_size,
                              hipStream_t stream) {
    const float* x = (const float*)d_in[0];
    const float* W = (const float*)d_in[1];
    float* out     = (float*)d_out;
    dim3 grid(IMG / TX, IMG / TY, 16 * 3);
    gauss2d_sep<<<grid, 256, 0, stream>>>(x, W, out);
}